// Round 1
// baseline (5294.260 us; speedup 1.0000x reference)
//
#include <hip/hip_runtime.h>
#include <math.h>

#define NN_ 20000
#define EE_ 320000

__device__ __forceinline__ float silu_f(float x) { return x / (1.0f + expf(-x)); }

// Fully-unrolled dense layer; weight indices are loop-constant -> scalar loads.
template<int IN, int OUT, bool ACT>
__device__ __forceinline__ void dense(const float* __restrict__ W,
                                      const float* __restrict__ in,
                                      float* __restrict__ out) {
  float acc[OUT];
#pragma unroll
  for (int j = 0; j < OUT; ++j) acc[j] = 0.f;
#pragma unroll
  for (int k = 0; k < IN; ++k) {
    const float x = in[k];
#pragma unroll
    for (int j = 0; j < OUT; ++j) acc[j] = fmaf(x, W[k * OUT + j], acc[j]);
  }
#pragma unroll
  for (int j = 0; j < OUT; ++j) out[j] = ACT ? silu_f(acc[j]) : acc[j];
}

// ---------------- K1: per-edge layer-1 (bessel + cutoff + radial MLP + scatter) ----
__global__ __launch_bounds__(256) void k1_edge(
    const float* __restrict__ disp, const int* __restrict__ species,
    const int* __restrict__ senders, const int* __restrict__ receivers,
    const float* __restrict__ lin1,
    const float* __restrict__ rw0, const float* __restrict__ rw1,
    const float* __restrict__ rw2, const float* __restrict__ rw3,
    float* __restrict__ agg_s, float* __restrict__ agg_v,
    float* __restrict__ rbc_g, float* __restrict__ y1_g) {
  const int e = blockIdx.x * 256 + threadIdx.x;
  const float dx = disp[e * 3 + 0], dy = disp[e * 3 + 1], dz = disp[e * 3 + 2];
  const float sq = dx * dx + dy * dy + dz * dz;
  const float rn = sqrtf(sq);
  const float inv = (rn == 0.f) ? 1.f : (1.f / rn);
  const float u = rn * 0.2f;  // r / CUTOFF
  float fc;
  {
    const float u2 = u * u;
    fc = 1.f - 6.f * u2 + 8.f * u2 * u - 3.f * u2 * u2;
    fc = (u < 1.f) ? fc : 0.f;
  }
  float rb[8];
#pragma unroll
  for (int k = 0; k < 8; ++k) {
    const float wk = (float)(k + 1) * 3.14159265358979323846f;
    const float s = (rn == 0.f) ? (wk * 0.2f) : (sinf(wk * u) * inv);
    rb[k] = 0.4f * s * fc;  // 2/CUTOFF = 0.4
  }
  float4 r0 = {rb[0], rb[1], rb[2], rb[3]};
  float4 r1 = {rb[4], rb[5], rb[6], rb[7]};
  *(float4*)(rbc_g + e * 8) = r0;
  *(float4*)(rbc_g + e * 8 + 4) = r1;
  const float y1x = 1.7320508075688772f * dx * inv;
  const float y1y = 1.7320508075688772f * dy * inv;
  const float y1z = 1.7320508075688772f * dz * inv;
  float4 y4 = {y1x, y1y, y1z, 0.f};
  *(float4*)(y1_g + e * 4) = y4;

  float ha[64], hb[64], R[16];
  dense<8, 64, true>(rw0, rb, ha);
  dense<64, 64, true>(rw1, ha, hb);
  dense<64, 64, true>(rw2, hb, ha);
  dense<64, 16, false>(rw3, ha, R);

  const int se = senders[e];
  const int r = receivers[e];
  const int sp = species[se];
  float s_[8];
#pragma unroll
  for (int c = 0; c < 8; ++c) s_[c] = lin1[sp * 8 + c];
  float* aggs = agg_s + r * 8;
  float* aggv = agg_v + r * 24;
#pragma unroll
  for (int c = 0; c < 8; ++c) atomicAdd(aggs + c, s_[c] * R[c]);
#pragma unroll
  for (int c = 0; c < 8; ++c) {
    const float m = s_[c] * R[8 + c];
    atomicAdd(aggv + c * 3 + 0, m * y1x);
    atomicAdd(aggv + c * 3 + 1, m * y1y);
    atomicAdd(aggv + c * 3 + 2, m * y1z);
  }
}

// ---------------- K2a: per-node layer-1 update (scal, x0, x1) ---------------------
__global__ __launch_bounds__(64) void k2a_node(
    const float* __restrict__ agg_s, const float* __restrict__ agg_v,
    const int* __restrict__ species,
    const float* __restrict__ w2s, const float* __restrict__ w2v,
    const float* __restrict__ skip1,
    float* __restrict__ x0_g, float* __restrict__ x1_g) {
  const int n = blockIdx.x;
  const int l = threadIdx.x;
  __shared__ float g_lds[128];
  const int sp = species[n];
  float as[8];
#pragma unroll
  for (int k = 0; k < 8; ++k) as[k] = agg_s[n * 8 + k] * 0.25f;
  float sc[4];
#pragma unroll
  for (int j = 0; j < 4; ++j) {
    const int d = l * 4 + j;
    float a = skip1[(sp * 9) * 256 + d];  // l1_skip[sp, sp, d]
#pragma unroll
    for (int k = 0; k < 8; ++k) a = fmaf(as[k], w2s[k * 256 + d], a);
    sc[j] = silu_f(a);
  }
  if (l < 32) {
#pragma unroll
    for (int j = 0; j < 4; ++j) x0_g[n * 128 + l * 4 + j] = sc[j];
  } else {
#pragma unroll
    for (int j = 0; j < 4; ++j) g_lds[(l - 32) * 4 + j] = sc[j];
  }
  __syncthreads();
  float av[24];
#pragma unroll
  for (int k = 0; k < 24; ++k) av[k] = agg_v[n * 24 + k] * 0.25f;
#pragma unroll
  for (int h = 0; h < 2; ++h) {
    const int d = l + h * 64;
    const float g = g_lds[d];
    float v0 = 0.f, v1 = 0.f, v2v = 0.f;
#pragma unroll
    for (int c = 0; c < 8; ++c) {
      const float w = w2v[c * 128 + d];
      v0 = fmaf(av[c * 3 + 0], w, v0);
      v1 = fmaf(av[c * 3 + 1], w, v1);
      v2v = fmaf(av[c * 3 + 2], w, v2v);
    }
    x1_g[(n * 3 + 0) * 128 + d] = v0 * g;
    x1_g[(n * 3 + 1) * 128 + d] = v1 * g;
    x1_g[(n * 3 + 2) * 128 + d] = v2v * g;
  }
}

// ---------------- K2b: node GEMMs (s2, v2, species-skip) --------------------------
__global__ __launch_bounds__(256) void k2b_gemm(
    const float* __restrict__ x0_g, const float* __restrict__ x1_g,
    const int* __restrict__ species,
    const float* __restrict__ lin1s, const float* __restrict__ lin1v,
    const float* __restrict__ skip2,
    float* __restrict__ s2_g, float* __restrict__ v2_g,
    float* __restrict__ skipv_g) {
  const int w = __builtin_amdgcn_readfirstlane((int)(threadIdx.x >> 6));
  const int l = threadIdx.x & 63;
  const int nbase = blockIdx.x * 32 + w * 8;
  float s2a[8] = {}, s2b[8] = {}, ska[8] = {}, skb[8] = {};
  float v2a[8][3] = {}, v2b[8][3] = {};
  int sp[8];
#pragma unroll
  for (int nn = 0; nn < 8; ++nn) sp[nn] = species[nbase + nn];
  for (int c = 0; c < 128; ++c) {
    const float wA0 = lin1s[c * 128 + l];
    const float wA1 = lin1s[c * 128 + 64 + l];
    const float wB0 = lin1v[c * 128 + l];
    const float wB1 = lin1v[c * 128 + 64 + l];
#pragma unroll
    for (int nn = 0; nn < 8; ++nn) {
      const int n = nbase + nn;
      const float x0v = x0_g[n * 128 + c];  // wave-uniform -> s_load
      const float wS0 = skip2[sp[nn] * 16384 + c * 128 + l];
      const float wS1 = skip2[sp[nn] * 16384 + c * 128 + 64 + l];
      s2a[nn] = fmaf(x0v, wA0, s2a[nn]);
      s2b[nn] = fmaf(x0v, wA1, s2b[nn]);
      ska[nn] = fmaf(x0v, wS0, ska[nn]);
      skb[nn] = fmaf(x0v, wS1, skb[nn]);
#pragma unroll
      for (int i = 0; i < 3; ++i) {
        const float x1v = x1_g[(n * 3 + i) * 128 + c];
        v2a[nn][i] = fmaf(x1v, wB0, v2a[nn][i]);
        v2b[nn][i] = fmaf(x1v, wB1, v2b[nn][i]);
      }
    }
  }
#pragma unroll
  for (int nn = 0; nn < 8; ++nn) {
    const int n = nbase + nn;
    s2_g[n * 128 + l] = s2a[nn];
    s2_g[n * 128 + 64 + l] = s2b[nn];
    skipv_g[n * 128 + l] = ska[nn];
    skipv_g[n * 128 + 64 + l] = skb[nn];
#pragma unroll
    for (int i = 0; i < 3; ++i) {
      v2_g[n * 384 + l * 3 + i] = v2a[nn][i];
      v2_g[n * 384 + (64 + l) * 3 + i] = v2b[nn][i];
    }
  }
}

// ---------------- K3: per-edge layer-2 (radial MLP + tp gather + scatter) ---------
__global__ __launch_bounds__(256) void k3_edge(
    const float* __restrict__ rbc_g, const float* __restrict__ y1_g,
    const int* __restrict__ senders, const int* __restrict__ receivers,
    const float* __restrict__ rw0, const float* __restrict__ rw1,
    const float* __restrict__ rw2, const float* __restrict__ rw3,
    const float* __restrict__ s2_g, const float* __restrict__ v2_g,
    float* __restrict__ agg2) {
  const int e = blockIdx.x * 256 + threadIdx.x;
  float rb[8];
  {
    const float4 a = *(const float4*)(rbc_g + e * 8);
    const float4 b = *(const float4*)(rbc_g + e * 8 + 4);
    rb[0] = a.x; rb[1] = a.y; rb[2] = a.z; rb[3] = a.w;
    rb[4] = b.x; rb[5] = b.y; rb[6] = b.z; rb[7] = b.w;
  }
  float ha[64], hb[64];
  dense<8, 64, true>(rw0, rb, ha);
  dense<64, 64, true>(rw1, ha, hb);
  dense<64, 64, true>(rw2, hb, ha);  // ha = h2 (live through head loop)

  const int s = senders[e];
  const int r = receivers[e];
  const float4 y4 = ((const float4*)y1_g)[e];
  const float* s2 = s2_g + s * 128;
  const float* v2b = v2_g + s * 384;
  float* aggr = agg2 + r * 256;
  const float inv_sqrt3 = 0.5773502691896258f;

  for (int jo = 0; jo < 16; ++jo) {  // runtime (uniform) chunk loop: 16 outputs/chunk
    float acc[16];
#pragma unroll
    for (int jj = 0; jj < 16; ++jj) acc[jj] = 0.f;
#pragma unroll
    for (int k = 0; k < 64; ++k) {
      const float x = ha[k];
#pragma unroll
      for (int jj = 0; jj < 16; ++jj)
        acc[jj] = fmaf(x, rw3[k * 256 + jo * 16 + jj], acc[jj]);
    }
    if (jo < 8) {  // tp = s2[sender] part
#pragma unroll
      for (int q = 0; q < 4; ++q) {
        const float4 v = *(const float4*)(s2 + jo * 16 + q * 4);
        atomicAdd(aggr + jo * 16 + q * 4 + 0, v.x * acc[q * 4 + 0]);
        atomicAdd(aggr + jo * 16 + q * 4 + 1, v.y * acc[q * 4 + 1]);
        atomicAdd(aggr + jo * 16 + q * 4 + 2, v.z * acc[q * 4 + 2]);
        atomicAdd(aggr + jo * 16 + q * 4 + 3, v.w * acc[q * 4 + 3]);
      }
    } else {  // tp = <v2[sender], Y1>/sqrt3 part
      const int cb = (jo - 8) * 16;
#pragma unroll
      for (int q = 0; q < 4; ++q) {
        const float4 a = *(const float4*)(v2b + (cb + q * 4) * 3 + 0);
        const float4 b = *(const float4*)(v2b + (cb + q * 4) * 3 + 4);
        const float4 c4 = *(const float4*)(v2b + (cb + q * 4) * 3 + 8);
        const float t0 = (a.x * y4.x + a.y * y4.y + a.z * y4.z) * inv_sqrt3;
        const float t1 = (a.w * y4.x + b.x * y4.y + b.y * y4.z) * inv_sqrt3;
        const float t2 = (b.z * y4.x + b.w * y4.y + c4.x * y4.z) * inv_sqrt3;
        const float t3 = (c4.y * y4.x + c4.z * y4.y + c4.w * y4.z) * inv_sqrt3;
        atomicAdd(aggr + 128 + cb + q * 4 + 0, t0 * acc[q * 4 + 0]);
        atomicAdd(aggr + 128 + cb + q * 4 + 1, t1 * acc[q * 4 + 1]);
        atomicAdd(aggr + 128 + cb + q * 4 + 2, t2 * acc[q * 4 + 2]);
        atomicAdd(aggr + 128 + cb + q * 4 + 3, t3 * acc[q * 4 + 3]);
      }
    }
  }
}

// ---------------- K4: final node update + readout ---------------------------------
__global__ __launch_bounds__(256) void k4_node(
    const float* __restrict__ agg2, const float* __restrict__ skipv,
    const float* __restrict__ w2, const float* __restrict__ readout,
    float* __restrict__ out) {
  __shared__ float tile[64 * 65];
  __shared__ float partial[256];
  const int t = threadIdx.x;
  const int w = __builtin_amdgcn_readfirstlane((int)(threadIdx.x >> 6));
  const int l = t & 63;
  const int n0 = blockIdx.x * 64;
  const int n = n0 + l;
  float acc[32];
#pragma unroll
  for (int j = 0; j < 32; ++j) acc[j] = 0.f;
  for (int ko = 0; ko < 256; ko += 64) {
    __syncthreads();
#pragma unroll
    for (int rep = 0; rep < 16; ++rep) {
      const int lin = rep * 256 + t;
      const int node = lin >> 6, kk = lin & 63;
      const int gn = n0 + node;
      tile[kk * 65 + node] = (gn < NN_) ? agg2[gn * 256 + ko + kk] * 0.25f : 0.f;
    }
    __syncthreads();
    for (int kk = 0; kk < 64; ++kk) {
      const float a = tile[kk * 65 + l];
#pragma unroll
      for (int jj = 0; jj < 32; ++jj)
        acc[jj] = fmaf(a, w2[(ko + kk) * 128 + w * 32 + jj], acc[jj]);
    }
  }
  float po = 0.f;
  if (n < NN_) {
#pragma unroll
    for (int jj = 0; jj < 32; ++jj) {
      const int d = w * 32 + jj;
      const float v = acc[jj] + skipv[n * 128 + d];
      po = fmaf(silu_f(v), readout[d], po);
    }
  }
  partial[w * 64 + l] = po;
  __syncthreads();
  if (t < 64 && n0 + t < NN_) {
    out[n0 + t] = partial[t] + partial[64 + t] + partial[128 + t] + partial[192 + t];
  }
}

extern "C" void kernel_launch(void* const* d_in, const int* in_sizes, int n_in,
                              void* d_out, int out_size, void* d_ws, size_t ws_size,
                              hipStream_t stream) {
  const float* disp = (const float*)d_in[0];
  const int* species = (const int*)d_in[1];
  const int* senders = (const int*)d_in[2];
  const int* receivers = (const int*)d_in[3];
  const float* l1_lin1 = (const float*)d_in[4];
  const float* l1_rw0 = (const float*)d_in[5];
  const float* l1_rw1 = (const float*)d_in[6];
  const float* l1_rw2 = (const float*)d_in[7];
  const float* l1_rw3 = (const float*)d_in[8];
  const float* l1_w2s = (const float*)d_in[9];
  const float* l1_w2v = (const float*)d_in[10];
  const float* l1_skip = (const float*)d_in[11];
  const float* l2_lin1s = (const float*)d_in[12];
  const float* l2_lin1v = (const float*)d_in[13];
  const float* l2_rw0 = (const float*)d_in[14];
  const float* l2_rw1 = (const float*)d_in[15];
  const float* l2_rw2 = (const float*)d_in[16];
  const float* l2_rw3 = (const float*)d_in[17];
  const float* l2_w2 = (const float*)d_in[18];
  const float* l2_skip = (const float*)d_in[19];
  const float* readout_w = (const float*)d_in[20];

  float* ws = (float*)d_ws;
  float* agg_s = ws;                   // N*8    = 160000
  float* agg_v = agg_s + 160000;       // N*24   = 480000
  float* agg2 = agg_v + 480000;        // N*256  = 5120000
  float* rbc = agg2 + 5120000;         // E*8    = 2560000
  float* y1 = rbc + 2560000;           // E*4    = 1280000
  float* x0 = y1 + 1280000;            // N*128  = 2560000
  float* x1 = x0 + 2560000;            // N*384  = 7680000
  float* s2 = x1 + 7680000;            // N*128  = 2560000
  float* v2 = s2 + 2560000;            // N*384  = 7680000
  float* skipv = v2 + 7680000;         // N*128  = 2560000

  // zero the atomic accumulators (agg_s | agg_v | agg2 are contiguous)
  hipMemsetAsync(ws, 0, (size_t)(160000 + 480000 + 5120000) * 4, stream);

  k1_edge<<<EE_ / 256, 256, 0, stream>>>(disp, species, senders, receivers,
                                         l1_lin1, l1_rw0, l1_rw1, l1_rw2, l1_rw3,
                                         agg_s, agg_v, rbc, y1);
  k2a_node<<<NN_, 64, 0, stream>>>(agg_s, agg_v, species, l1_w2s, l1_w2v, l1_skip,
                                   x0, x1);
  k2b_gemm<<<NN_ / 32, 256, 0, stream>>>(x0, x1, species, l2_lin1s, l2_lin1v,
                                         l2_skip, s2, v2, skipv);
  k3_edge<<<EE_ / 256, 256, 0, stream>>>(rbc, y1, senders, receivers, l2_rw0,
                                         l2_rw1, l2_rw2, l2_rw3, s2, v2, agg2);
  k4_node<<<(NN_ + 63) / 64, 256, 0, stream>>>(agg2, skipv, l2_w2, readout_w,
                                               (float*)d_out);
}

// Round 2
// 1309.538 us; speedup vs baseline: 4.0428x; 4.0428x over previous
//
#include <hip/hip_runtime.h>
#include <math.h>

#define NN_ 20000
#define EE_ 320000

__device__ __forceinline__ float silu_f(float x) { return x / (1.0f + expf(-x)); }

// Fully-unrolled dense layer; weight indices are loop-constant -> scalar loads.
template<int IN, int OUT, bool ACT>
__device__ __forceinline__ void dense(const float* __restrict__ W,
                                      const float* __restrict__ in,
                                      float* __restrict__ out) {
  float acc[OUT];
#pragma unroll
  for (int j = 0; j < OUT; ++j) acc[j] = 0.f;
#pragma unroll
  for (int k = 0; k < IN; ++k) {
    const float x = in[k];
#pragma unroll
    for (int j = 0; j < OUT; ++j) acc[j] = fmaf(x, W[k * OUT + j], acc[j]);
  }
#pragma unroll
  for (int j = 0; j < OUT; ++j) out[j] = ACT ? silu_f(acc[j]) : acc[j];
}

// ================= CSR construction (receiver-sorted edge ids) ====================
__global__ __launch_bounds__(256) void k_hist(const int* __restrict__ receivers,
                                              int* __restrict__ hist) {
  const int e = blockIdx.x * 256 + threadIdx.x;
  atomicAdd(&hist[receivers[e]], 1);
}

__global__ __launch_bounds__(1024) void k_scan(const int* __restrict__ hist,
                                               int* __restrict__ offs,
                                               int* __restrict__ cursor) {
  __shared__ int lds[1024];
  __shared__ int carry_s;
  const int t = threadIdx.x;
  if (t == 0) carry_s = 0;
  __syncthreads();
  for (int base = 0; base < NN_; base += 1024) {
    const int i = base + t;
    const int v = (i < NN_) ? hist[i] : 0;
    lds[t] = v;
    __syncthreads();
    for (int d = 1; d < 1024; d <<= 1) {
      const int tv = (t >= d) ? lds[t - d] : 0;
      __syncthreads();
      lds[t] += tv;
      __syncthreads();
    }
    const int inc = lds[t];  // inclusive scan of this chunk
    const int c = carry_s;
    if (i < NN_) {
      const int off = c + inc - v;
      offs[i] = off;
      cursor[i] = off;
    }
    __syncthreads();
    if (t == 0) carry_s = c + lds[1023];
    __syncthreads();
  }
  if (t == 0) offs[NN_] = carry_s;
}

__global__ __launch_bounds__(256) void k_scatter(const int* __restrict__ receivers,
                                                 int* __restrict__ cursor,
                                                 int* __restrict__ edge_id) {
  const int e = blockIdx.x * 256 + threadIdx.x;
  const int r = receivers[e];
  const int pos = atomicAdd(&cursor[r], 1);
  edge_id[pos] = e;
}

// ---------------- K1a: per-edge layer-1 (bessel + cutoff + radial MLP + msg) ------
__global__ __launch_bounds__(256) void k1a_edge(
    const float* __restrict__ disp, const int* __restrict__ species,
    const int* __restrict__ senders,
    const float* __restrict__ lin1,
    const float* __restrict__ rw0, const float* __restrict__ rw1,
    const float* __restrict__ rw2, const float* __restrict__ rw3,
    float* __restrict__ buf1, float* __restrict__ rbc_g, float* __restrict__ y1_g) {
  const int e = blockIdx.x * 256 + threadIdx.x;
  const float dx = disp[e * 3 + 0], dy = disp[e * 3 + 1], dz = disp[e * 3 + 2];
  const float sq = dx * dx + dy * dy + dz * dz;
  const float rn = sqrtf(sq);
  const float inv = (rn == 0.f) ? 1.f : (1.f / rn);
  const float u = rn * 0.2f;  // r / CUTOFF
  float fc;
  {
    const float u2 = u * u;
    fc = 1.f - 6.f * u2 + 8.f * u2 * u - 3.f * u2 * u2;
    fc = (u < 1.f) ? fc : 0.f;
  }
  float rb[8];
#pragma unroll
  for (int k = 0; k < 8; ++k) {
    const float wk = (float)(k + 1) * 3.14159265358979323846f;
    const float s = (rn == 0.f) ? (wk * 0.2f) : (sinf(wk * u) * inv);
    rb[k] = 0.4f * s * fc;  // 2/CUTOFF = 0.4
  }
  float4 r0 = {rb[0], rb[1], rb[2], rb[3]};
  float4 r1 = {rb[4], rb[5], rb[6], rb[7]};
  *(float4*)(rbc_g + e * 8) = r0;
  *(float4*)(rbc_g + e * 8 + 4) = r1;
  const float y1x = 1.7320508075688772f * dx * inv;
  const float y1y = 1.7320508075688772f * dy * inv;
  const float y1z = 1.7320508075688772f * dz * inv;
  float4 y4 = {y1x, y1y, y1z, 0.f};
  *(float4*)(y1_g + e * 4) = y4;

  float h0[64], h1[64], R[16];
  dense<8, 64, true>(rw0, rb, h0);
  dense<64, 64, true>(rw1, h0, h1);
  dense<64, 64, true>(rw2, h1, h0);
  dense<64, 16, false>(rw3, h0, R);

  const int sp = species[senders[e]];
  float m[32];
#pragma unroll
  for (int c = 0; c < 8; ++c) {
    const float sc = lin1[sp * 8 + c];
    m[c] = sc * R[c];
    const float mv = sc * R[8 + c];
    m[8 + c * 3 + 0] = mv * y1x;
    m[8 + c * 3 + 1] = mv * y1y;
    m[8 + c * 3 + 2] = mv * y1z;
  }
  float* dst = buf1 + (size_t)e * 32;
#pragma unroll
  for (int q = 0; q < 8; ++q) {
    float4 v = {m[q * 4 + 0], m[q * 4 + 1], m[q * 4 + 2], m[q * 4 + 3]};
    *(float4*)(dst + q * 4) = v;
  }
}

// ---------------- K1b: per-node gather of layer-1 messages ------------------------
__global__ __launch_bounds__(256) void k1b_gather(
    const float* __restrict__ buf1, const int* __restrict__ offs,
    const int* __restrict__ edge_id,
    float* __restrict__ agg_s, float* __restrict__ agg_v) {
  const int n = blockIdx.x * 8 + (threadIdx.x >> 5);
  const int ch = threadIdx.x & 31;
  const int beg = offs[n], end = offs[n + 1];
  float acc = 0.f;
  for (int i = beg; i < end; ++i) {
    const int eid = edge_id[i];
    acc += buf1[(size_t)eid * 32 + ch];
  }
  if (ch < 8) agg_s[n * 8 + ch] = acc;
  else agg_v[n * 24 + (ch - 8)] = acc;
}

// ---------------- K2a: per-node layer-1 update (scal, x0, x1) ---------------------
__global__ __launch_bounds__(64) void k2a_node(
    const float* __restrict__ agg_s, const float* __restrict__ agg_v,
    const int* __restrict__ species,
    const float* __restrict__ w2s, const float* __restrict__ w2v,
    const float* __restrict__ skip1,
    float* __restrict__ x0_g, float* __restrict__ x1_g) {
  const int n = blockIdx.x;
  const int l = threadIdx.x;
  __shared__ float g_lds[128];
  const int sp = species[n];
  float as[8];
#pragma unroll
  for (int k = 0; k < 8; ++k) as[k] = agg_s[n * 8 + k] * 0.25f;
  float sc[4];
#pragma unroll
  for (int j = 0; j < 4; ++j) {
    const int d = l * 4 + j;
    float a = skip1[(sp * 9) * 256 + d];  // l1_skip[sp, sp, d]
#pragma unroll
    for (int k = 0; k < 8; ++k) a = fmaf(as[k], w2s[k * 256 + d], a);
    sc[j] = silu_f(a);
  }
  if (l < 32) {
#pragma unroll
    for (int j = 0; j < 4; ++j) x0_g[n * 128 + l * 4 + j] = sc[j];
  } else {
#pragma unroll
    for (int j = 0; j < 4; ++j) g_lds[(l - 32) * 4 + j] = sc[j];
  }
  __syncthreads();
  float av[24];
#pragma unroll
  for (int k = 0; k < 24; ++k) av[k] = agg_v[n * 24 + k] * 0.25f;
#pragma unroll
  for (int h = 0; h < 2; ++h) {
    const int d = l + h * 64;
    const float g = g_lds[d];
    float v0 = 0.f, v1 = 0.f, v2v = 0.f;
#pragma unroll
    for (int c = 0; c < 8; ++c) {
      const float w = w2v[c * 128 + d];
      v0 = fmaf(av[c * 3 + 0], w, v0);
      v1 = fmaf(av[c * 3 + 1], w, v1);
      v2v = fmaf(av[c * 3 + 2], w, v2v);
    }
    x1_g[(n * 3 + 0) * 128 + d] = v0 * g;
    x1_g[(n * 3 + 1) * 128 + d] = v1 * g;
    x1_g[(n * 3 + 2) * 128 + d] = v2v * g;
  }
}

// ---------------- K2b: node GEMMs (s2, v2, species-skip) --------------------------
__global__ __launch_bounds__(256) void k2b_gemm(
    const float* __restrict__ x0_g, const float* __restrict__ x1_g,
    const int* __restrict__ species,
    const float* __restrict__ lin1s, const float* __restrict__ lin1v,
    const float* __restrict__ skip2,
    float* __restrict__ s2_g, float* __restrict__ v2_g,
    float* __restrict__ skipv_g) {
  const int w = __builtin_amdgcn_readfirstlane((int)(threadIdx.x >> 6));
  const int l = threadIdx.x & 63;
  const int nbase = blockIdx.x * 32 + w * 8;
  float s2a[8] = {}, s2b[8] = {}, ska[8] = {}, skb[8] = {};
  float v2a[8][3] = {}, v2b[8][3] = {};
  int sp[8];
#pragma unroll
  for (int nn = 0; nn < 8; ++nn) sp[nn] = species[nbase + nn];
  for (int c = 0; c < 128; ++c) {
    const float wA0 = lin1s[c * 128 + l];
    const float wA1 = lin1s[c * 128 + 64 + l];
    const float wB0 = lin1v[c * 128 + l];
    const float wB1 = lin1v[c * 128 + 64 + l];
#pragma unroll
    for (int nn = 0; nn < 8; ++nn) {
      const int n = nbase + nn;
      const float x0v = x0_g[n * 128 + c];  // wave-uniform -> s_load
      const float wS0 = skip2[sp[nn] * 16384 + c * 128 + l];
      const float wS1 = skip2[sp[nn] * 16384 + c * 128 + 64 + l];
      s2a[nn] = fmaf(x0v, wA0, s2a[nn]);
      s2b[nn] = fmaf(x0v, wA1, s2b[nn]);
      ska[nn] = fmaf(x0v, wS0, ska[nn]);
      skb[nn] = fmaf(x0v, wS1, skb[nn]);
#pragma unroll
      for (int i = 0; i < 3; ++i) {
        const float x1v = x1_g[(n * 3 + i) * 128 + c];
        v2a[nn][i] = fmaf(x1v, wB0, v2a[nn][i]);
        v2b[nn][i] = fmaf(x1v, wB1, v2b[nn][i]);
      }
    }
  }
#pragma unroll
  for (int nn = 0; nn < 8; ++nn) {
    const int n = nbase + nn;
    s2_g[n * 128 + l] = s2a[nn];
    s2_g[n * 128 + 64 + l] = s2b[nn];
    skipv_g[n * 128 + l] = ska[nn];
    skipv_g[n * 128 + 64 + l] = skb[nn];
#pragma unroll
    for (int i = 0; i < 3; ++i) {
      v2_g[n * 384 + l * 3 + i] = v2a[nn][i];
      v2_g[n * 384 + (64 + l) * 3 + i] = v2b[nn][i];
    }
  }
}

// ---------------- K3a: per-edge layer-2 radial MLP body (8->64->64->64) -----------
__global__ __launch_bounds__(256) void k3a_edge(
    const float* __restrict__ rbc_g,
    const float* __restrict__ rw0, const float* __restrict__ rw1,
    const float* __restrict__ rw2,
    float* __restrict__ ha_buf) {
  const int e = blockIdx.x * 256 + threadIdx.x;
  float rb[8];
  {
    const float4 a = *(const float4*)(rbc_g + e * 8);
    const float4 b = *(const float4*)(rbc_g + e * 8 + 4);
    rb[0] = a.x; rb[1] = a.y; rb[2] = a.z; rb[3] = a.w;
    rb[4] = b.x; rb[5] = b.y; rb[6] = b.z; rb[7] = b.w;
  }
  float h0[64], h1[64];
  dense<8, 64, true>(rw0, rb, h0);
  dense<64, 64, true>(rw1, h0, h1);
  dense<64, 64, true>(rw2, h1, h0);
  float* dst = ha_buf + (size_t)e * 64;
#pragma unroll
  for (int q = 0; q < 16; ++q) {
    float4 v = {h0[q * 4 + 0], h0[q * 4 + 1], h0[q * 4 + 2], h0[q * 4 + 3]};
    *(float4*)(dst + q * 4) = v;
  }
}

// ---------------- K3b: per-node gather + 64->256 head + tensor product ------------
__global__ __launch_bounds__(256) void k3b_gather(
    const float* __restrict__ ha_buf, const float* __restrict__ y1_g,
    const int* __restrict__ senders,
    const int* __restrict__ offs, const int* __restrict__ edge_id,
    const float* __restrict__ rw3,
    const float* __restrict__ s2_g, const float* __restrict__ v2_g,
    float* __restrict__ agg2) {
  const int n = blockIdx.x;
  const int ch = threadIdx.x;
  float w[64];  // rw3 column for this output channel, register-resident
#pragma unroll
  for (int k = 0; k < 64; ++k) w[k] = rw3[k * 256 + ch];
  const int beg = offs[n], end = offs[n + 1];
  const bool is_s = ch < 128;
  const int c3 = (ch - 128) * 3;
  float acc = 0.f;
  for (int i = beg; i < end; ++i) {
    const int eid = __builtin_amdgcn_readfirstlane(edge_id[i]);
    const int s = __builtin_amdgcn_readfirstlane(senders[eid]);
    const float y1x = y1_g[eid * 4 + 0];
    const float y1y = y1_g[eid * 4 + 1];
    const float y1z = y1_g[eid * 4 + 2];
    float tp;
    if (is_s) {
      tp = s2_g[(size_t)s * 128 + ch];
    } else {
      tp = (v2_g[(size_t)s * 384 + c3 + 0] * y1x +
            v2_g[(size_t)s * 384 + c3 + 1] * y1y +
            v2_g[(size_t)s * 384 + c3 + 2] * y1z) * 0.5773502691896258f;
    }
    const float* ha = ha_buf + (size_t)eid * 64;  // uniform base -> scalar loads
    float r0 = 0.f, r1 = 0.f, r2 = 0.f, r3 = 0.f;
#pragma unroll
    for (int k = 0; k < 64; k += 4) {
      r0 = fmaf(ha[k + 0], w[k + 0], r0);
      r1 = fmaf(ha[k + 1], w[k + 1], r1);
      r2 = fmaf(ha[k + 2], w[k + 2], r2);
      r3 = fmaf(ha[k + 3], w[k + 3], r3);
    }
    acc = fmaf(tp, (r0 + r1) + (r2 + r3), acc);
  }
  agg2[(size_t)n * 256 + ch] = acc;  // raw sum; k4 applies 1/sqrt(AVG_N)... = 0.25
}

// ---------------- K4: final node update + readout ---------------------------------
__global__ __launch_bounds__(256) void k4_node(
    const float* __restrict__ agg2, const float* __restrict__ skipv,
    const float* __restrict__ w2, const float* __restrict__ readout,
    float* __restrict__ out) {
  __shared__ float tile[64 * 65];
  __shared__ float partial[256];
  const int t = threadIdx.x;
  const int w = __builtin_amdgcn_readfirstlane((int)(threadIdx.x >> 6));
  const int l = t & 63;
  const int n0 = blockIdx.x * 64;
  const int n = n0 + l;
  float acc[32];
#pragma unroll
  for (int j = 0; j < 32; ++j) acc[j] = 0.f;
  for (int ko = 0; ko < 256; ko += 64) {
    __syncthreads();
#pragma unroll
    for (int rep = 0; rep < 16; ++rep) {
      const int lin = rep * 256 + t;
      const int node = lin >> 6, kk = lin & 63;
      const int gn = n0 + node;
      tile[kk * 65 + node] = (gn < NN_) ? agg2[(size_t)gn * 256 + ko + kk] * 0.25f : 0.f;
    }
    __syncthreads();
    for (int kk = 0; kk < 64; ++kk) {
      const float a = tile[kk * 65 + l];
#pragma unroll
      for (int jj = 0; jj < 32; ++jj)
        acc[jj] = fmaf(a, w2[(ko + kk) * 128 + w * 32 + jj], acc[jj]);
    }
  }
  float po = 0.f;
  if (n < NN_) {
#pragma unroll
    for (int jj = 0; jj < 32; ++jj) {
      const int d = w * 32 + jj;
      const float v = acc[jj] + skipv[n * 128 + d];
      po = fmaf(silu_f(v), readout[d], po);
    }
  }
  partial[w * 64 + l] = po;
  __syncthreads();
  if (t < 64 && n0 + t < NN_) {
    out[n0 + t] = partial[t] + partial[64 + t] + partial[128 + t] + partial[192 + t];
  }
}

extern "C" void kernel_launch(void* const* d_in, const int* in_sizes, int n_in,
                              void* d_out, int out_size, void* d_ws, size_t ws_size,
                              hipStream_t stream) {
  const float* disp = (const float*)d_in[0];
  const int* species = (const int*)d_in[1];
  const int* senders = (const int*)d_in[2];
  const int* receivers = (const int*)d_in[3];
  const float* l1_lin1 = (const float*)d_in[4];
  const float* l1_rw0 = (const float*)d_in[5];
  const float* l1_rw1 = (const float*)d_in[6];
  const float* l1_rw2 = (const float*)d_in[7];
  const float* l1_rw3 = (const float*)d_in[8];
  const float* l1_w2s = (const float*)d_in[9];
  const float* l1_w2v = (const float*)d_in[10];
  const float* l1_skip = (const float*)d_in[11];
  const float* l2_lin1s = (const float*)d_in[12];
  const float* l2_lin1v = (const float*)d_in[13];
  const float* l2_rw0 = (const float*)d_in[14];
  const float* l2_rw1 = (const float*)d_in[15];
  const float* l2_rw2 = (const float*)d_in[16];
  const float* l2_rw3 = (const float*)d_in[17];
  const float* l2_w2 = (const float*)d_in[18];
  const float* l2_skip = (const float*)d_in[19];
  const float* readout_w = (const float*)d_in[20];

  // ---- workspace layout (elements), with lifetime overlays in `pool` ----
  float* ws = (float*)d_ws;
  float* rbc   = ws;               // E*8  = 2,560,000  [k1a -> k3a]
  float* y1    = ws + 2560000;     // E*4  = 1,280,000  [k1a -> k3b]
  float* s2    = ws + 3840000;     // N*128= 2,560,000  [k2b -> k3b]
  float* v2    = ws + 6400000;     // N*384= 7,680,000  [k2b -> k3b]
  float* skipv = ws + 14080000;    // N*128= 2,560,000  [k2b -> k4]
  float* agg2  = ws + 16640000;    // N*256= 5,120,000  [k3b -> k4]
  float* pool  = ws + 21760000;    // 20,480,000 shared pool:
  float* agg_s = pool;             //   N*8  [k1b -> k2a]
  float* agg_v = pool + 160000;    //   N*24 [k1b -> k2a]
  float* buf1  = pool + 640000;    //   E*32 [k1a -> k1b]
  float* x0    = pool + 640000;    //   N*128 [k2a -> k2b] (over dead buf1)
  float* x1    = pool + 3200000;   //   N*384 [k2a -> k2b]
  float* ha    = pool;             //   E*64 [k3a -> k3b] (over all of the above)
  int* ibase   = (int*)(ws + 42240000);
  int* hist    = ibase;            // N
  int* cursor  = ibase + 20000;    // N
  int* offs    = ibase + 40000;    // N+1
  int* edge_id = ibase + 60001;    // E
  // total = (42,240,000 + 380,001) * 4 B = 170.5 MB
  if (ws_size < (size_t)(42240000 + 380001) * 4) return;  // fail loudly, no scribble

  // ---- CSR build ----
  hipMemsetAsync(hist, 0, 20000 * sizeof(int), stream);
  k_hist<<<EE_ / 256, 256, 0, stream>>>(receivers, hist);
  k_scan<<<1, 1024, 0, stream>>>(hist, offs, cursor);
  k_scatter<<<EE_ / 256, 256, 0, stream>>>(receivers, cursor, edge_id);

  // ---- layer 1 ----
  k1a_edge<<<EE_ / 256, 256, 0, stream>>>(disp, species, senders, l1_lin1,
                                          l1_rw0, l1_rw1, l1_rw2, l1_rw3,
                                          buf1, rbc, y1);
  k1b_gather<<<NN_ / 8, 256, 0, stream>>>(buf1, offs, edge_id, agg_s, agg_v);
  k2a_node<<<NN_, 64, 0, stream>>>(agg_s, agg_v, species, l1_w2s, l1_w2v, l1_skip,
                                   x0, x1);
  k2b_gemm<<<NN_ / 32, 256, 0, stream>>>(x0, x1, species, l2_lin1s, l2_lin1v,
                                         l2_skip, s2, v2, skipv);

  // ---- layer 2 ----
  k3a_edge<<<EE_ / 256, 256, 0, stream>>>(rbc, l2_rw0, l2_rw1, l2_rw2, ha);
  k3b_gather<<<NN_, 256, 0, stream>>>(ha, y1, senders, offs, edge_id, l2_rw3,
                                      s2, v2, agg2);
  k4_node<<<(NN_ + 63) / 64, 256, 0, stream>>>(agg2, skipv, l2_w2, readout_w,
                                               (float*)d_out);
}

// Round 3
// 1091.603 us; speedup vs baseline: 4.8500x; 1.1996x over previous
//
#include <hip/hip_runtime.h>
#include <math.h>

#define NN_ 20000
#define EE_ 320000
#define SHP 68  // padded row stride (floats) for [128][SHP] activation tile; 16B-aligned

__device__ __forceinline__ float silu_f(float x) { return x / (1.0f + expf(-x)); }

// ---- GEMM-tiled dense layer over a 128-edge LDS tile --------------------------
// Block = 128 threads = 2 waves. Wave w owns rows [w*64, w*64+64).
// Lane: eg = l>>3, jg = l&7. Thread tile: 8 edges (stride 8) x 8 outs.
// sh_h layout [edge][SHP]; sh_w flat [KD*64], row-major [k][64].
// In-place: all reads precede writes in wave program order; waves own disjoint rows.
template<int KD>
__device__ __forceinline__ void layer_step(float* __restrict__ sh_h,
                                           const float* __restrict__ sh_w,
                                           int wavebase, int eg, int jg) {
  const int jb = jg * 8;
  float acc[8][8];
#pragma unroll
  for (int ee = 0; ee < 8; ++ee)
#pragma unroll
    for (int jj = 0; jj < 8; ++jj) acc[ee][jj] = 0.f;

#pragma unroll
  for (int kc = 0; kc < KD; kc += 4) {
    float4 w4[4][2];
#pragma unroll
    for (int kk = 0; kk < 4; ++kk) {
      w4[kk][0] = *(const float4*)&sh_w[(kc + kk) * 64 + jb];
      w4[kk][1] = *(const float4*)&sh_w[(kc + kk) * 64 + jb + 4];
    }
    float4 h4[8];
#pragma unroll
    for (int ee = 0; ee < 8; ++ee)
      h4[ee] = *(const float4*)&sh_h[(wavebase + eg + 8 * ee) * SHP + kc];
#pragma unroll
    for (int kk = 0; kk < 4; ++kk) {
#pragma unroll
      for (int ee = 0; ee < 8; ++ee) {
        const float hv = ((const float*)&h4[ee])[kk];
        acc[ee][0] = fmaf(hv, w4[kk][0].x, acc[ee][0]);
        acc[ee][1] = fmaf(hv, w4[kk][0].y, acc[ee][1]);
        acc[ee][2] = fmaf(hv, w4[kk][0].z, acc[ee][2]);
        acc[ee][3] = fmaf(hv, w4[kk][0].w, acc[ee][3]);
        acc[ee][4] = fmaf(hv, w4[kk][1].x, acc[ee][4]);
        acc[ee][5] = fmaf(hv, w4[kk][1].y, acc[ee][5]);
        acc[ee][6] = fmaf(hv, w4[kk][1].z, acc[ee][6]);
        acc[ee][7] = fmaf(hv, w4[kk][1].w, acc[ee][7]);
      }
    }
  }
#pragma unroll
  for (int ee = 0; ee < 8; ++ee) {
    float* dst = &sh_h[(wavebase + eg + 8 * ee) * SHP + jb];
    float4 lo = {silu_f(acc[ee][0]), silu_f(acc[ee][1]), silu_f(acc[ee][2]), silu_f(acc[ee][3])};
    float4 hi = {silu_f(acc[ee][4]), silu_f(acc[ee][5]), silu_f(acc[ee][6]), silu_f(acc[ee][7])};
    *(float4*)dst = lo;
    *(float4*)(dst + 4) = hi;
  }
}

__device__ __forceinline__ void load_w(const float* __restrict__ W, int nfloat,
                                       float* __restrict__ dst, int t) {
  for (int i = t * 4; i < nfloat; i += 512) *(float4*)(dst + i) = *(const float4*)(W + i);
}

// ================= CSR construction (receiver-sorted edge ids) ====================
__global__ __launch_bounds__(256) void k_hist(const int* __restrict__ receivers,
                                              int* __restrict__ hist) {
  const int e = blockIdx.x * 256 + threadIdx.x;
  atomicAdd(&hist[receivers[e]], 1);
}

__global__ __launch_bounds__(1024) void k_scan(const int* __restrict__ hist,
                                               int* __restrict__ offs,
                                               int* __restrict__ cursor) {
  __shared__ int lds[1024];
  __shared__ int carry_s;
  const int t = threadIdx.x;
  if (t == 0) carry_s = 0;
  __syncthreads();
  for (int base = 0; base < NN_; base += 1024) {
    const int i = base + t;
    const int v = (i < NN_) ? hist[i] : 0;
    lds[t] = v;
    __syncthreads();
    for (int d = 1; d < 1024; d <<= 1) {
      const int tv = (t >= d) ? lds[t - d] : 0;
      __syncthreads();
      lds[t] += tv;
      __syncthreads();
    }
    const int inc = lds[t];
    const int c = carry_s;
    if (i < NN_) {
      const int off = c + inc - v;
      offs[i] = off;
      cursor[i] = off;
    }
    __syncthreads();
    if (t == 0) carry_s = c + lds[1023];
    __syncthreads();
  }
  if (t == 0) offs[NN_] = carry_s;
}

__global__ __launch_bounds__(256) void k_scatter(const int* __restrict__ receivers,
                                                 int* __restrict__ cursor,
                                                 int* __restrict__ edge_id) {
  const int e = blockIdx.x * 256 + threadIdx.x;
  const int r = receivers[e];
  const int pos = atomicAdd(&cursor[r], 1);
  edge_id[pos] = e;
}

// ---------------- K1a: per-edge layer-1 (geometry + tiled radial MLP + msg) -------
__global__ __launch_bounds__(128) void k1a_radial(
    const float* __restrict__ disp, const int* __restrict__ species,
    const int* __restrict__ senders,
    const float* __restrict__ lin1,
    const float* __restrict__ rw0, const float* __restrict__ rw1,
    const float* __restrict__ rw2, const float* __restrict__ rw3,
    float* __restrict__ buf1, float* __restrict__ rbc_g, float* __restrict__ y1_g) {
  __shared__ float sh_h[128 * SHP];
  __shared__ float sh_w[64 * 64];
  const int t = threadIdx.x;
  const int e0 = blockIdx.x * 128;
  const int e = e0 + t;

  // ---- geometry (thread t <-> edge e0+t) ----
  const float dx = disp[e * 3 + 0], dy = disp[e * 3 + 1], dz = disp[e * 3 + 2];
  const float sq = dx * dx + dy * dy + dz * dz;
  const float rn = sqrtf(sq);
  const float inv = (rn == 0.f) ? 1.f : (1.f / rn);
  const float u = rn * 0.2f;
  float fc;
  {
    const float u2 = u * u;
    fc = 1.f - 6.f * u2 + 8.f * u2 * u - 3.f * u2 * u2;
    fc = (u < 1.f) ? fc : 0.f;
  }
  float rb[8];
#pragma unroll
  for (int k = 0; k < 8; ++k) {
    const float wk = (float)(k + 1) * 3.14159265358979323846f;
    const float s = (rn == 0.f) ? (wk * 0.2f) : (sinf(wk * u) * inv);
    rb[k] = 0.4f * s * fc;
  }
  float4 r0 = {rb[0], rb[1], rb[2], rb[3]};
  float4 r1 = {rb[4], rb[5], rb[6], rb[7]};
  *(float4*)(rbc_g + e * 8) = r0;
  *(float4*)(rbc_g + e * 8 + 4) = r1;
  const float y1x = 1.7320508075688772f * dx * inv;
  const float y1y = 1.7320508075688772f * dy * inv;
  const float y1z = 1.7320508075688772f * dz * inv;
  float4 y4 = {y1x, y1y, y1z, 0.f};
  *(float4*)(y1_g + e * 4) = y4;
  *(float4*)&sh_h[t * SHP] = r0;
  *(float4*)&sh_h[t * SHP + 4] = r1;

  // ---- tiled MLP ----
  const int wavebase = (t >> 6) * 64;
  const int lane = t & 63;
  const int eg = lane >> 3, jg = lane & 7;

  load_w(rw0, 8 * 64, sh_w, t);
  __syncthreads();
  layer_step<8>(sh_h, sh_w, wavebase, eg, jg);
  __syncthreads();
  load_w(rw1, 64 * 64, sh_w, t);
  __syncthreads();
  layer_step<64>(sh_h, sh_w, wavebase, eg, jg);
  __syncthreads();
  load_w(rw2, 64 * 64, sh_w, t);
  __syncthreads();
  layer_step<64>(sh_h, sh_w, wavebase, eg, jg);
  __syncthreads();

  // ---- head 64->16 (thread t <-> edge t; rw3 via scalar loads) ----
  float R[16];
#pragma unroll
  for (int c = 0; c < 16; ++c) R[c] = 0.f;
  for (int k = 0; k < 64; ++k) {
    const float h = sh_h[t * SHP + k];
#pragma unroll
    for (int c = 0; c < 16; ++c) R[c] = fmaf(h, rw3[k * 16 + c], R[c]);
  }

  // ---- messages ----
  const int sp = species[senders[e]];
  float m[32];
#pragma unroll
  for (int c = 0; c < 8; ++c) {
    const float sc = lin1[sp * 8 + c];
    m[c] = sc * R[c];
    const float mv = sc * R[8 + c];
    m[8 + c * 3 + 0] = mv * y1x;
    m[8 + c * 3 + 1] = mv * y1y;
    m[8 + c * 3 + 2] = mv * y1z;
  }
  float* dst = buf1 + (size_t)e * 32;
#pragma unroll
  for (int q = 0; q < 8; ++q) {
    float4 v = {m[q * 4 + 0], m[q * 4 + 1], m[q * 4 + 2], m[q * 4 + 3]};
    *(float4*)(dst + q * 4) = v;
  }
}

// ---------------- K3a: per-edge layer-2 radial MLP body (tiled) -------------------
__global__ __launch_bounds__(128) void k3a_radial(
    const float* __restrict__ rbc_g,
    const float* __restrict__ rw0, const float* __restrict__ rw1,
    const float* __restrict__ rw2,
    float* __restrict__ ha_buf) {
  __shared__ float sh_h[128 * SHP];
  __shared__ float sh_w[64 * 64];
  const int t = threadIdx.x;
  const int e0 = blockIdx.x * 128;

  *(float4*)&sh_h[t * SHP] = *(const float4*)(rbc_g + (size_t)(e0 + t) * 8);
  *(float4*)&sh_h[t * SHP + 4] = *(const float4*)(rbc_g + (size_t)(e0 + t) * 8 + 4);

  const int wavebase = (t >> 6) * 64;
  const int lane = t & 63;
  const int eg = lane >> 3, jg = lane & 7;

  load_w(rw0, 8 * 64, sh_w, t);
  __syncthreads();
  layer_step<8>(sh_h, sh_w, wavebase, eg, jg);
  __syncthreads();
  load_w(rw1, 64 * 64, sh_w, t);
  __syncthreads();
  layer_step<64>(sh_h, sh_w, wavebase, eg, jg);
  __syncthreads();
  load_w(rw2, 64 * 64, sh_w, t);
  __syncthreads();
  layer_step<64>(sh_h, sh_w, wavebase, eg, jg);
  __syncthreads();

  // ---- write h2 tile to global, coalesced ----
#pragma unroll
  for (int r = 0; r < 16; ++r) {
    const int lin = r * 128 + t;
    const int el = lin >> 4;
    const int k = (lin & 15) * 4;
    *(float4*)(ha_buf + (size_t)(e0 + el) * 64 + k) = *(const float4*)&sh_h[el * SHP + k];
  }
}

// ---------------- K1b: per-node gather of layer-1 messages ------------------------
__global__ __launch_bounds__(256) void k1b_gather(
    const float* __restrict__ buf1, const int* __restrict__ offs,
    const int* __restrict__ edge_id,
    float* __restrict__ agg_s, float* __restrict__ agg_v) {
  const int n = blockIdx.x * 8 + (threadIdx.x >> 5);
  const int ch = threadIdx.x & 31;
  const int beg = offs[n], end = offs[n + 1];
  float acc = 0.f;
  for (int i = beg; i < end; ++i) {
    const int eid = edge_id[i];
    acc += buf1[(size_t)eid * 32 + ch];
  }
  if (ch < 8) agg_s[n * 8 + ch] = acc;
  else agg_v[n * 24 + (ch - 8)] = acc;
}

// ---------------- K2a: per-node layer-1 update (scal, x0, x1) ---------------------
__global__ __launch_bounds__(64) void k2a_node(
    const float* __restrict__ agg_s, const float* __restrict__ agg_v,
    const int* __restrict__ species,
    const float* __restrict__ w2s, const float* __restrict__ w2v,
    const float* __restrict__ skip1,
    float* __restrict__ x0_g, float* __restrict__ x1_g) {
  const int n = blockIdx.x;
  const int l = threadIdx.x;
  __shared__ float g_lds[128];
  const int sp = species[n];
  float as[8];
#pragma unroll
  for (int k = 0; k < 8; ++k) as[k] = agg_s[n * 8 + k] * 0.25f;
  float sc[4];
#pragma unroll
  for (int j = 0; j < 4; ++j) {
    const int d = l * 4 + j;
    float a = skip1[(sp * 9) * 256 + d];
#pragma unroll
    for (int k = 0; k < 8; ++k) a = fmaf(as[k], w2s[k * 256 + d], a);
    sc[j] = silu_f(a);
  }
  if (l < 32) {
#pragma unroll
    for (int j = 0; j < 4; ++j) x0_g[n * 128 + l * 4 + j] = sc[j];
  } else {
#pragma unroll
    for (int j = 0; j < 4; ++j) g_lds[(l - 32) * 4 + j] = sc[j];
  }
  __syncthreads();
  float av[24];
#pragma unroll
  for (int k = 0; k < 24; ++k) av[k] = agg_v[n * 24 + k] * 0.25f;
#pragma unroll
  for (int h = 0; h < 2; ++h) {
    const int d = l + h * 64;
    const float g = g_lds[d];
    float v0 = 0.f, v1 = 0.f, v2v = 0.f;
#pragma unroll
    for (int c = 0; c < 8; ++c) {
      const float w = w2v[c * 128 + d];
      v0 = fmaf(av[c * 3 + 0], w, v0);
      v1 = fmaf(av[c * 3 + 1], w, v1);
      v2v = fmaf(av[c * 3 + 2], w, v2v);
    }
    x1_g[(n * 3 + 0) * 128 + d] = v0 * g;
    x1_g[(n * 3 + 1) * 128 + d] = v1 * g;
    x1_g[(n * 3 + 2) * 128 + d] = v2v * g;
  }
}

// ---------------- K2b: node GEMMs (s2, v2, species-skip) --------------------------
__global__ __launch_bounds__(256) void k2b_gemm(
    const float* __restrict__ x0_g, const float* __restrict__ x1_g,
    const int* __restrict__ species,
    const float* __restrict__ lin1s, const float* __restrict__ lin1v,
    const float* __restrict__ skip2,
    float* __restrict__ s2_g, float* __restrict__ v2_g,
    float* __restrict__ skipv_g) {
  const int w = __builtin_amdgcn_readfirstlane((int)(threadIdx.x >> 6));
  const int l = threadIdx.x & 63;
  const int nbase = blockIdx.x * 32 + w * 8;
  float s2a[8] = {}, s2b[8] = {}, ska[8] = {}, skb[8] = {};
  float v2a[8][3] = {}, v2b[8][3] = {};
  int sp[8];
#pragma unroll
  for (int nn = 0; nn < 8; ++nn) sp[nn] = species[nbase + nn];
  for (int c = 0; c < 128; ++c) {
    const float wA0 = lin1s[c * 128 + l];
    const float wA1 = lin1s[c * 128 + 64 + l];
    const float wB0 = lin1v[c * 128 + l];
    const float wB1 = lin1v[c * 128 + 64 + l];
#pragma unroll
    for (int nn = 0; nn < 8; ++nn) {
      const int n = nbase + nn;
      const float x0v = x0_g[n * 128 + c];
      const float wS0 = skip2[sp[nn] * 16384 + c * 128 + l];
      const float wS1 = skip2[sp[nn] * 16384 + c * 128 + 64 + l];
      s2a[nn] = fmaf(x0v, wA0, s2a[nn]);
      s2b[nn] = fmaf(x0v, wA1, s2b[nn]);
      ska[nn] = fmaf(x0v, wS0, ska[nn]);
      skb[nn] = fmaf(x0v, wS1, skb[nn]);
#pragma unroll
      for (int i = 0; i < 3; ++i) {
        const float x1v = x1_g[(n * 3 + i) * 128 + c];
        v2a[nn][i] = fmaf(x1v, wB0, v2a[nn][i]);
        v2b[nn][i] = fmaf(x1v, wB1, v2b[nn][i]);
      }
    }
  }
#pragma unroll
  for (int nn = 0; nn < 8; ++nn) {
    const int n = nbase + nn;
    s2_g[n * 128 + l] = s2a[nn];
    s2_g[n * 128 + 64 + l] = s2b[nn];
    skipv_g[n * 128 + l] = ska[nn];
    skipv_g[n * 128 + 64 + l] = skb[nn];
#pragma unroll
    for (int i = 0; i < 3; ++i) {
      v2_g[n * 384 + l * 3 + i] = v2a[nn][i];
      v2_g[n * 384 + (64 + l) * 3 + i] = v2b[nn][i];
    }
  }
}

// ---------------- K3b: per-node gather + 64->256 head + tensor product ------------
__global__ __launch_bounds__(256) void k3b_gather(
    const float* __restrict__ ha_buf, const float* __restrict__ y1_g,
    const int* __restrict__ senders,
    const int* __restrict__ offs, const int* __restrict__ edge_id,
    const float* __restrict__ rw3,
    const float* __restrict__ s2_g, const float* __restrict__ v2_g,
    float* __restrict__ agg2) {
  const int n = blockIdx.x;
  const int ch = threadIdx.x;
  float w[64];
#pragma unroll
  for (int k = 0; k < 64; ++k) w[k] = rw3[k * 256 + ch];
  const int beg = offs[n], end = offs[n + 1];
  const bool is_s = ch < 128;
  const int c3 = (ch - 128) * 3;
  float acc = 0.f;
  for (int i = beg; i < end; ++i) {
    const int eid = __builtin_amdgcn_readfirstlane(edge_id[i]);
    const int s = __builtin_amdgcn_readfirstlane(senders[eid]);
    const float y1x = y1_g[eid * 4 + 0];
    const float y1y = y1_g[eid * 4 + 1];
    const float y1z = y1_g[eid * 4 + 2];
    float tp;
    if (is_s) {
      tp = s2_g[(size_t)s * 128 + ch];
    } else {
      tp = (v2_g[(size_t)s * 384 + c3 + 0] * y1x +
            v2_g[(size_t)s * 384 + c3 + 1] * y1y +
            v2_g[(size_t)s * 384 + c3 + 2] * y1z) * 0.5773502691896258f;
    }
    const float* ha = ha_buf + (size_t)eid * 64;
    float r0 = 0.f, r1 = 0.f, r2 = 0.f, r3 = 0.f;
#pragma unroll
    for (int k = 0; k < 64; k += 4) {
      r0 = fmaf(ha[k + 0], w[k + 0], r0);
      r1 = fmaf(ha[k + 1], w[k + 1], r1);
      r2 = fmaf(ha[k + 2], w[k + 2], r2);
      r3 = fmaf(ha[k + 3], w[k + 3], r3);
    }
    acc = fmaf(tp, (r0 + r1) + (r2 + r3), acc);
  }
  agg2[(size_t)n * 256 + ch] = acc;
}

// ---------------- K4: final node update + readout ---------------------------------
__global__ __launch_bounds__(256) void k4_node(
    const float* __restrict__ agg2, const float* __restrict__ skipv,
    const float* __restrict__ w2, const float* __restrict__ readout,
    float* __restrict__ out) {
  __shared__ float tile[64 * 65];
  __shared__ float partial[256];
  const int t = threadIdx.x;
  const int w = __builtin_amdgcn_readfirstlane((int)(threadIdx.x >> 6));
  const int l = t & 63;
  const int n0 = blockIdx.x * 64;
  const int n = n0 + l;
  float acc[32];
#pragma unroll
  for (int j = 0; j < 32; ++j) acc[j] = 0.f;
  for (int ko = 0; ko < 256; ko += 64) {
    __syncthreads();
#pragma unroll
    for (int rep = 0; rep < 16; ++rep) {
      const int lin = rep * 256 + t;
      const int node = lin >> 6, kk = lin & 63;
      const int gn = n0 + node;
      tile[kk * 65 + node] = (gn < NN_) ? agg2[(size_t)gn * 256 + ko + kk] * 0.25f : 0.f;
    }
    __syncthreads();
    for (int kk = 0; kk < 64; ++kk) {
      const float a = tile[kk * 65 + l];
#pragma unroll
      for (int jj = 0; jj < 32; ++jj)
        acc[jj] = fmaf(a, w2[(ko + kk) * 128 + w * 32 + jj], acc[jj]);
    }
  }
  float po = 0.f;
  if (n < NN_) {
#pragma unroll
    for (int jj = 0; jj < 32; ++jj) {
      const int d = w * 32 + jj;
      const float v = acc[jj] + skipv[n * 128 + d];
      po = fmaf(silu_f(v), readout[d], po);
    }
  }
  partial[w * 64 + l] = po;
  __syncthreads();
  if (t < 64 && n0 + t < NN_) {
    out[n0 + t] = partial[t] + partial[64 + t] + partial[128 + t] + partial[192 + t];
  }
}

extern "C" void kernel_launch(void* const* d_in, const int* in_sizes, int n_in,
                              void* d_out, int out_size, void* d_ws, size_t ws_size,
                              hipStream_t stream) {
  const float* disp = (const float*)d_in[0];
  const int* species = (const int*)d_in[1];
  const int* senders = (const int*)d_in[2];
  const int* receivers = (const int*)d_in[3];
  const float* l1_lin1 = (const float*)d_in[4];
  const float* l1_rw0 = (const float*)d_in[5];
  const float* l1_rw1 = (const float*)d_in[6];
  const float* l1_rw2 = (const float*)d_in[7];
  const float* l1_rw3 = (const float*)d_in[8];
  const float* l1_w2s = (const float*)d_in[9];
  const float* l1_w2v = (const float*)d_in[10];
  const float* l1_skip = (const float*)d_in[11];
  const float* l2_lin1s = (const float*)d_in[12];
  const float* l2_lin1v = (const float*)d_in[13];
  const float* l2_rw0 = (const float*)d_in[14];
  const float* l2_rw1 = (const float*)d_in[15];
  const float* l2_rw2 = (const float*)d_in[16];
  const float* l2_rw3 = (const float*)d_in[17];
  const float* l2_w2 = (const float*)d_in[18];
  const float* l2_skip = (const float*)d_in[19];
  const float* readout_w = (const float*)d_in[20];

  // ---- workspace layout (elements), with lifetime overlays in `pool` ----
  float* ws = (float*)d_ws;
  float* rbc   = ws;               // E*8  [k1a -> k3a]
  float* y1    = ws + 2560000;     // E*4  [k1a -> k3b]
  float* s2    = ws + 3840000;     // N*128 [k2b -> k3b]
  float* v2    = ws + 6400000;     // N*384 [k2b -> k3b]
  float* skipv = ws + 14080000;    // N*128 [k2b -> k4]
  float* agg2  = ws + 16640000;    // N*256 [k3b -> k4]
  float* pool  = ws + 21760000;    // shared pool:
  float* agg_s = pool;             //   N*8   [k1b -> k2a]
  float* agg_v = pool + 160000;    //   N*24  [k1b -> k2a]
  float* buf1  = pool + 640000;    //   E*32  [k1a -> k1b]
  float* x0    = pool + 640000;    //   N*128 [k2a -> k2b] (over dead buf1)
  float* x1    = pool + 3200000;   //   N*384 [k2a -> k2b]
  float* ha    = pool;             //   E*64  [k3a -> k3b]
  int* ibase   = (int*)(ws + 42240000);
  int* hist    = ibase;            // N
  int* cursor  = ibase + 20000;    // N
  int* offs    = ibase + 40000;    // N+1
  int* edge_id = ibase + 60001;    // E
  if (ws_size < (size_t)(42240000 + 380001) * 4) return;  // fail loudly, no scribble

  // ---- CSR build ----
  hipMemsetAsync(hist, 0, 20000 * sizeof(int), stream);
  k_hist<<<EE_ / 256, 256, 0, stream>>>(receivers, hist);
  k_scan<<<1, 1024, 0, stream>>>(hist, offs, cursor);
  k_scatter<<<EE_ / 256, 256, 0, stream>>>(receivers, cursor, edge_id);

  // ---- layer 1 ----
  k1a_radial<<<EE_ / 128, 128, 0, stream>>>(disp, species, senders, l1_lin1,
                                            l1_rw0, l1_rw1, l1_rw2, l1_rw3,
                                            buf1, rbc, y1);
  k1b_gather<<<NN_ / 8, 256, 0, stream>>>(buf1, offs, edge_id, agg_s, agg_v);
  k2a_node<<<NN_, 64, 0, stream>>>(agg_s, agg_v, species, l1_w2s, l1_w2v, l1_skip,
                                   x0, x1);
  k2b_gemm<<<NN_ / 32, 256, 0, stream>>>(x0, x1, species, l2_lin1s, l2_lin1v,
                                         l2_skip, s2, v2, skipv);

  // ---- layer 2 ----
  k3a_radial<<<EE_ / 128, 128, 0, stream>>>(rbc, l2_rw0, l2_rw1, l2_rw2, ha);
  k3b_gather<<<NN_, 256, 0, stream>>>(ha, y1, senders, offs, edge_id, l2_rw3,
                                      s2, v2, agg2);
  k4_node<<<(NN_ + 63) / 64, 256, 0, stream>>>(agg2, skipv, l2_w2, readout_w,
                                               (float*)d_out);
}